// Round 1
// baseline (101.186 us; speedup 1.0000x reference)
//
#include <hip/hip_runtime.h>

// MoE: out[b] = inp[b] @ weight[gate[b]].T
// inp:    [4096, 512] f32
// gate:   [4096] int
// weight: [32, 512, 512] f32  (expert, out_feat, in_feat)
// out:    [4096, 512] f32

#define NE     32
#define NBATCH 4096
#define KF     512   // IN_FEAT
#define NF     512   // OUT_FEAT
#define BM     64    // token tile
#define BN     64    // out-feature tile
#define BK     32    // k tile
#define MAXTILES (NBATCH / BM + NE)   // 96: worst-case sum of ceil(cnt_e/BM)

// ws int layout: [0..31] counts, [32..64] offsets(33), [72..103] cursors,
//                [128..128+4096) token indices sorted by expert
#define WS_COUNTS  0
#define WS_OFFSETS 32
#define WS_CURSORS 72
#define WS_TOKENS  128

__global__ void moe_zero(int* ws) {
    if (threadIdx.x < NE) ws[WS_COUNTS + threadIdx.x] = 0;
}

__global__ void moe_hist(const int* __restrict__ gate, int* __restrict__ ws) {
    int b = blockIdx.x * blockDim.x + threadIdx.x;
    if (b < NBATCH) atomicAdd(&ws[WS_COUNTS + gate[b]], 1);
}

__global__ void moe_scan(int* ws) {
    if (threadIdx.x == 0) {
        int acc = 0;
        for (int e = 0; e < NE; ++e) {
            ws[WS_OFFSETS + e] = acc;
            ws[WS_CURSORS + e] = acc;
            acc += ws[WS_COUNTS + e];
        }
        ws[WS_OFFSETS + NE] = acc;
    }
}

__global__ void moe_scatter(const int* __restrict__ gate, int* __restrict__ ws) {
    int b = blockIdx.x * blockDim.x + threadIdx.x;
    if (b < NBATCH) {
        int e = gate[b];
        int pos = atomicAdd(&ws[WS_CURSORS + e], 1);
        ws[WS_TOKENS + pos] = b;
    }
}

__global__ __launch_bounds__(256)
void moe_gemm(const float* __restrict__ inp,
              const float* __restrict__ weight,
              const int* __restrict__ ws,
              float* __restrict__ out) {
    const int* counts  = ws + WS_COUNTS;
    const int* offsets = ws + WS_OFFSETS;
    const int* tokens  = ws + WS_TOKENS;

    // Map blockIdx.y -> (expert, local token-tile)
    int tileY = blockIdx.y;
    int e = -1, local = 0, acc = 0;
    for (int i = 0; i < NE; ++i) {
        int t = (counts[i] + BM - 1) / BM;
        if (tileY < acc + t) { e = i; local = tileY - acc; break; }
        acc += t;
    }
    if (e < 0) return;

    const int off  = offsets[e];
    const int cnt  = counts[e];
    const int m0   = local * BM;
    const int mcnt = min(BM, cnt - m0);
    const int nblk = blockIdx.x * BN;

    __shared__ float As[BM][BK + 1];
    __shared__ float Wsm[BN][BK + 1];
    __shared__ int   srow[BM];

    const int tid = threadIdx.x;
    if (tid < BM) srow[tid] = (tid < mcnt) ? tokens[off + m0 + tid] : -1;
    __syncthreads();

    const int tx = tid & 15;         // n dimension
    const int ty = tid >> 4;         // m dimension
    const int tx4 = tx * 4, ty4 = ty * 4;

    const float* wbase = weight + (size_t)e * NF * KF + (size_t)nblk * KF;

    float accf[4][4];
#pragma unroll
    for (int i = 0; i < 4; ++i)
#pragma unroll
        for (int j = 0; j < 4; ++j) accf[i][j] = 0.f;

    for (int k0 = 0; k0 < KF; k0 += BK) {
#pragma unroll
        for (int l = 0; l < 2; ++l) {
            int idx = tid + l * 256;       // 512 float4 slots: 64 rows x 8
            int r = idx >> 3, c4 = idx & 7;
            // A tile (gathered token rows)
            int row = srow[r];
            float4 va = make_float4(0.f, 0.f, 0.f, 0.f);
            if (row >= 0)
                va = *(const float4*)(inp + (size_t)row * KF + k0 + c4 * 4);
            As[r][c4 * 4 + 0] = va.x;
            As[r][c4 * 4 + 1] = va.y;
            As[r][c4 * 4 + 2] = va.z;
            As[r][c4 * 4 + 3] = va.w;
            // W tile
            float4 vw = *(const float4*)(wbase + (size_t)r * KF + k0 + c4 * 4);
            Wsm[r][c4 * 4 + 0] = vw.x;
            Wsm[r][c4 * 4 + 1] = vw.y;
            Wsm[r][c4 * 4 + 2] = vw.z;
            Wsm[r][c4 * 4 + 3] = vw.w;
        }
        __syncthreads();

#pragma unroll
        for (int k = 0; k < BK; ++k) {
            float a[4], b[4];
#pragma unroll
            for (int i = 0; i < 4; ++i) a[i] = As[ty4 + i][k];
#pragma unroll
            for (int j = 0; j < 4; ++j) b[j] = Wsm[tx4 + j][k];
#pragma unroll
            for (int i = 0; i < 4; ++i)
#pragma unroll
                for (int j = 0; j < 4; ++j) accf[i][j] += a[i] * b[j];
        }
        __syncthreads();
    }

#pragma unroll
    for (int i = 0; i < 4; ++i) {
        int row = srow[ty4 + i];
        if (row >= 0) {
            float4 v = make_float4(accf[i][0], accf[i][1], accf[i][2], accf[i][3]);
            *(float4*)(out + (size_t)row * NF + nblk + tx4) = v;
        }
    }
}

extern "C" void kernel_launch(void* const* d_in, const int* in_sizes, int n_in,
                              void* d_out, int out_size, void* d_ws, size_t ws_size,
                              hipStream_t stream) {
    const float* inp    = (const float*)d_in[0];
    const int*   gate   = (const int*)d_in[1];
    const float* weight = (const float*)d_in[2];
    float*       out    = (float*)d_out;
    int*         ws     = (int*)d_ws;

    moe_zero<<<1, 64, 0, stream>>>(ws);
    moe_hist<<<NBATCH / 256, 256, 0, stream>>>(gate, ws);
    moe_scan<<<1, 64, 0, stream>>>(ws);
    moe_scatter<<<NBATCH / 256, 256, 0, stream>>>(gate, ws);

    dim3 grid(NF / BN, MAXTILES);
    moe_gemm<<<grid, 256, 0, stream>>>(inp, weight, ws, out);
}

// Round 2
// 30.246 us; speedup vs baseline: 3.3454x; 3.3454x over previous
//
#include <hip/hip_runtime.h>

// MoE: out[b] = inp[b] @ weight[gate[b]].T
// inp: [4096,512] f32, gate: [4096] int, weight: [32,512,512] f32, out: [4096,512] f32
// Strategy: sort tokens by expert (1 fused prep kernel), then grouped bf16-MFMA GEMM
// with on-the-fly f32->bf16 conversion during reg-staged LDS writes (XOR-swizzled).

#define NE     32
#define NBATCH 4096
#define KF     512
#define NF     512
#define BM     64            // token tile
#define BN     128           // out-feature tile
#define BK     64            // k tile
#define NKT    (KF / BK)     // 8
#define MAXTILES (NBATCH / BM + NE)   // 96 worst-case tiles

#define WS_COUNTS  0
#define WS_OFFSETS 32
#define WS_TOKENS  128

typedef __attribute__((ext_vector_type(8))) short bf16x8;   // 8 bf16 = 4 VGPR
typedef __attribute__((ext_vector_type(4))) float f32x4;

__device__ __forceinline__ unsigned short f2bf(float x) {
    union { float f; unsigned u; } a; a.f = x;
    unsigned r = a.u + 0x7FFFu + ((a.u >> 16) & 1u);   // RNE
    return (unsigned short)(r >> 16);
}

// XOR swizzle within a [row][64 bf16] row-major tile (row stride 128B).
// Applied identically on write (b64) and read (b128) -> functionally safe bijection.
__device__ __forceinline__ int swz(int row, int col_b) {
    return (row * 128 + col_b) ^ ((row & 7) << 4);
}

// ---- fused prep: histogram + scan + scatter, one block ----
__global__ __launch_bounds__(1024)
void moe_prep(const int* __restrict__ gate, int* __restrict__ ws) {
    __shared__ int cnt[NE], off[NE], cur[NE];
    const int tid = threadIdx.x;
    if (tid < NE) cnt[tid] = 0;
    __syncthreads();
    int g[4];
#pragma unroll
    for (int i = 0; i < 4; ++i) {
        g[i] = gate[tid + i * 1024];
        atomicAdd(&cnt[g[i]], 1);
    }
    __syncthreads();
    if (tid == 0) {
        int acc = 0;
        for (int e = 0; e < NE; ++e) { off[e] = acc; acc += cnt[e]; }
    }
    __syncthreads();
    if (tid < NE) {
        cur[tid] = off[tid];
        ws[WS_COUNTS + tid]  = cnt[tid];
        ws[WS_OFFSETS + tid] = off[tid];
    }
    __syncthreads();
#pragma unroll
    for (int i = 0; i < 4; ++i) {
        int pos = atomicAdd(&cur[g[i]], 1);
        ws[WS_TOKENS + pos] = tid + i * 1024;
    }
}

// ---- grouped MFMA GEMM ----
__global__ __launch_bounds__(256)
void moe_gemm(const float* __restrict__ inp,
              const float* __restrict__ weight,
              const int* __restrict__ ws,
              float* __restrict__ out) {
    const int* counts  = ws + WS_COUNTS;
    const int* offsets = ws + WS_OFFSETS;
    const int* tokens  = ws + WS_TOKENS;

    // map blockIdx.y -> (expert, local token-tile)
    int tileY = blockIdx.y;
    int e = -1, local = 0, acc_t = 0;
    for (int i = 0; i < NE; ++i) {
        int t = (counts[i] + BM - 1) / BM;
        if (tileY < acc_t + t) { e = i; local = tileY - acc_t; break; }
        acc_t += t;
    }
    if (e < 0) return;

    const int off  = offsets[e];
    const int cnt  = counts[e];
    const int m0   = local * BM;
    const int mcnt = min(BM, cnt - m0);
    const int nblk = blockIdx.x * BN;

    __shared__ __align__(16) unsigned char lds[2][(BM + BN) * BK * 2]; // A 8KB + W 16KB per buf
    __shared__ int srow[BM];

    const int tid  = threadIdx.x;
    const int lane = tid & 63;
    const int wid  = tid >> 6;
    const int wm   = wid & 1;    // m half (32 rows)
    const int wn   = wid >> 1;   // n half (64 cols)

    if (tid < BM) srow[tid] = (tid < mcnt) ? tokens[off + m0 + tid] : -1;
    __syncthreads();

    // cache the 4 gathered A-row ids this thread stages
    int arow[4];
#pragma unroll
    for (int i = 0; i < 4; ++i) arow[i] = srow[(tid >> 4) + 16 * i];

    const float* wbase = weight + (size_t)e * (NF * KF) + (size_t)nblk * KF;

    float4 ra[4], rw[8];

#define LOAD_TILE(T) do { const int k0 = (T) * BK;                                   \
    _Pragma("unroll") for (int i = 0; i < 4; ++i) {                                  \
        int c = tid & 15;                                                            \
        ra[i] = (arow[i] >= 0)                                                       \
            ? *(const float4*)(inp + (size_t)arow[i] * KF + k0 + c * 4)              \
            : make_float4(0.f, 0.f, 0.f, 0.f); }                                     \
    _Pragma("unroll") for (int i = 0; i < 8; ++i) {                                  \
        int s = tid + i * 256; int r = s >> 4, c = s & 15;                           \
        rw[i] = *(const float4*)(wbase + (size_t)r * KF + k0 + c * 4); } } while (0)

#define WRITE_TILE(B) do { unsigned char* Lb = lds[B];                               \
    _Pragma("unroll") for (int i = 0; i < 4; ++i) {                                  \
        int s = tid + i * 256; int r = s >> 4, c = s & 15;                           \
        union { unsigned short u[4]; uint2 v; } p;                                   \
        p.u[0] = f2bf(ra[i].x); p.u[1] = f2bf(ra[i].y);                              \
        p.u[2] = f2bf(ra[i].z); p.u[3] = f2bf(ra[i].w);                              \
        *(uint2*)(Lb + swz(r, c * 8)) = p.v; }                                       \
    _Pragma("unroll") for (int i = 0; i < 8; ++i) {                                  \
        int s = tid + i * 256; int r = s >> 4, c = s & 15;                           \
        union { unsigned short u[4]; uint2 v; } p;                                   \
        p.u[0] = f2bf(rw[i].x); p.u[1] = f2bf(rw[i].y);                              \
        p.u[2] = f2bf(rw[i].z); p.u[3] = f2bf(rw[i].w);                              \
        *(uint2*)(Lb + 8192 + swz(r, c * 8)) = p.v; } } while (0)

    f32x4 acc[2][4];
#pragma unroll
    for (int mi = 0; mi < 2; ++mi)
#pragma unroll
        for (int ni = 0; ni < 4; ++ni) acc[mi][ni] = (f32x4)(0.f);

#define COMPUTE(B) do { const unsigned char* Lb = lds[B];                            \
    _Pragma("unroll") for (int kk = 0; kk < 2; ++kk) {                               \
        const int kb = kk * 64 + 16 * (lane >> 4);                                   \
        bf16x8 af[2], bfr[4];                                                        \
        _Pragma("unroll") for (int mi = 0; mi < 2; ++mi) {                           \
            int r = wm * 32 + mi * 16 + (lane & 15);                                 \
            af[mi] = *(const bf16x8*)(Lb + swz(r, kb)); }                            \
        _Pragma("unroll") for (int ni = 0; ni < 4; ++ni) {                           \
            int r = wn * 64 + ni * 16 + (lane & 15);                                 \
            bfr[ni] = *(const bf16x8*)(Lb + 8192 + swz(r, kb)); }                    \
        _Pragma("unroll") for (int mi = 0; mi < 2; ++mi)                             \
        _Pragma("unroll") for (int ni = 0; ni < 4; ++ni)                             \
            acc[mi][ni] = __builtin_amdgcn_mfma_f32_16x16x32_bf16(                   \
                af[mi], bfr[ni], acc[mi][ni], 0, 0, 0); } } while (0)

    LOAD_TILE(0);
    WRITE_TILE(0);
    __syncthreads();
    int cur = 0;
    for (int t = 0; t < NKT; ++t) {
        if (t + 1 < NKT) LOAD_TILE(t + 1);   // issue-early (latency hides under MFMA)
        COMPUTE(cur);
        __syncthreads();
        if (t + 1 < NKT) WRITE_TILE(cur ^ 1); // write-late
        __syncthreads();
        cur ^= 1;
    }

    // epilogue: D frag layout col=lane&15, row=(lane>>4)*4+q  [m89-verified]
#pragma unroll
    for (int mi = 0; mi < 2; ++mi)
#pragma unroll
        for (int ni = 0; ni < 4; ++ni)
#pragma unroll
            for (int q = 0; q < 4; ++q) {
                int m = wm * 32 + mi * 16 + (lane >> 4) * 4 + q;
                int row = srow[m];
                if (row >= 0)
                    out[(size_t)row * NF + nblk + wn * 64 + ni * 16 + (lane & 15)]
                        = acc[mi][ni][q];
            }
}

extern "C" void kernel_launch(void* const* d_in, const int* in_sizes, int n_in,
                              void* d_out, int out_size, void* d_ws, size_t ws_size,
                              hipStream_t stream) {
    const float* inp    = (const float*)d_in[0];
    const int*   gate   = (const int*)d_in[1];
    const float* weight = (const float*)d_in[2];
    float*       out    = (float*)d_out;
    int*         ws     = (int*)d_ws;

    moe_prep<<<1, 1024, 0, stream>>>(gate, ws);

    dim3 grid(NF / BN, MAXTILES);
    moe_gemm<<<grid, 256, 0, stream>>>(inp, weight, ws, out);
}